// Round 11
// baseline (201.364 us; speedup 1.0000x reference)
//
#include <hip/hip_runtime.h>
#include <hip/hip_bf16.h>
#include <hip/hip_fp16.h>

#define IN_FT  128
#define OUT_FT 32
#define APITCH 136   // f16 pitch for A tile

typedef _Float16 f16x8 __attribute__((ext_vector_type(8)));
typedef _Float16 f16x2 __attribute__((ext_vector_type(2)));
typedef __attribute__((ext_vector_type(4))) float f32x4;

union H2 { unsigned u; _Float16 h[2]; };

// ---- swizzled f16 weight fragment table (16 KB), 8 blocks ----
// wtab[tile][kt][lane][j] = w[kt*32 + (lane>>4)*8 + j][(lane&15) + tile*16]
__global__ __launch_bounds__(256) void gcn_swz(const float* __restrict__ w,
                                               _Float16* __restrict__ wtab) {
    int i0 = blockIdx.x * 1024;
    for (int k = 0; k < 4; ++k) {
        int i = i0 + k * 256 + threadIdx.x;
        int j    = i & 7;
        int lane = (i >> 3) & 63;
        int kt   = (i >> 9) & 3;
        int tile = i >> 11;
        int kk   = kt * 32 + (lane >> 4) * 8 + j;
        int c    = (lane & 15) + tile * 16;
        wtab[i] = (_Float16)w[kk * OUT_FT + c];
    }
}

// ---- sup(f16) = seq @ w via MFMA; LDS-staged A; 16B-store epilogue ----
__global__ __launch_bounds__(256) void gcn_gemm_mfma(const float* __restrict__ seq,
                                                     const _Float16* __restrict__ wtab,
                                                     unsigned short* __restrict__ sup,
                                                     unsigned short* __restrict__ accb,
                                                     int n) {
    __shared__ __align__(16) _Float16 at[64 * APITCH];   // 17 KB
    __shared__ __align__(16) _Float16 sh[64 * OUT_FT];   // 4 KB epilogue buffer
    const int t    = threadIdx.x;
    const int base = blockIdx.x * 64;

    // zero this block's 64-row slice of the f16 accumulator (64 x 64 B)
    {
        int row = base + (t >> 2);
        if (row < n) {
            uint4 z = make_uint4(0, 0, 0, 0);
            ((uint4*)(accb + (size_t)row * OUT_FT))[t & 3] = z;
        }
    }

    // stage A tile: 64 rows x 128 f32 -> f16, coalesced global reads
    for (int it = 0; it < 4; ++it) {
        int i     = it * 256 + t;
        int row_l = i >> 4;
        int c     = i & 15;
        int row   = base + row_l;
        f16x8 v = (f16x8)0;
        if (row < n) {
            const float4* p = (const float4*)(seq + (size_t)row * IN_FT + c * 8);
            float4 lo = p[0], hi = p[1];
            v[0] = (_Float16)lo.x; v[1] = (_Float16)lo.y;
            v[2] = (_Float16)lo.z; v[3] = (_Float16)lo.w;
            v[4] = (_Float16)hi.x; v[5] = (_Float16)hi.y;
            v[6] = (_Float16)hi.z; v[7] = (_Float16)hi.w;
        }
        *(f16x8*)&at[row_l * APITCH + c * 8] = v;
    }
    __syncthreads();

    const int wave = t >> 6;
    const int lane = t & 63;
    const int m    = lane & 15;
    const int quad = lane >> 4;

    const f16x8* wt = (const f16x8*)wtab;
    const int arow_l = wave * 16 + m;

    f32x4 acc0 = {0.f, 0.f, 0.f, 0.f};
    f32x4 acc1 = {0.f, 0.f, 0.f, 0.f};

    for (int kt = 0; kt < 4; ++kt) {
        f16x8 a  = *(const f16x8*)&at[arow_l * APITCH + kt * 32 + quad * 8];
        f16x8 b0 = wt[(0 * 4 + kt) * 64 + lane];
        f16x8 b1 = wt[(1 * 4 + kt) * 64 + lane];
        acc0 = __builtin_amdgcn_mfma_f32_16x16x32_f16(a, b0, acc0, 0, 0, 0);
        acc1 = __builtin_amdgcn_mfma_f32_16x16x32_f16(a, b1, acc1, 0, 0, 0);
    }

    // epilogue: C/D (col=lane&15, row=quad*4+reg) -> LDS -> 16B coalesced stores
    for (int i = 0; i < 4; ++i) {
        int rl = wave * 16 + quad * 4 + i;
        sh[rl * OUT_FT + m]      = (_Float16)acc0[i];
        sh[rl * OUT_FT + 16 + m] = (_Float16)acc1[i];
    }
    __syncthreads();
    {
        int rl  = t >> 2;
        int row = base + rl;
        if (row < n)
            ((uint4*)(sup + (size_t)row * OUT_FT))[t & 3] =
                ((const uint4*)(sh + rl * OUT_FT))[t & 3];
    }
}

// ---- scatter: thread = (edge, col-pair); ONE pk_add_f16 atomic per thread --
__global__ __launch_bounds__(256) void gcn_scatter_h2(const int* __restrict__ erow,
                                                      const int* __restrict__ ecol,
                                                      const float* __restrict__ eval,
                                                      const unsigned short* __restrict__ sup,
                                                      unsigned short* __restrict__ accb,
                                                      int ebase, int eend) {
    long long g = (long long)blockIdx.x * 256 + threadIdx.x;
    int e  = ebase + (int)(g >> 4);
    int cp = (int)(g & 15);
    if (e >= eend) return;
    int   r  = erow[e];
    int   cl = ecol[e];
    float v  = eval[e];
    H2 s; s.u = ((const unsigned*)(sup + (size_t)cl * OUT_FT))[cp];
    f16x2 msg;
    msg[0] = (_Float16)(v * (float)s.h[0]);
    msg[1] = (_Float16)(v * (float)s.h[1]);
    f16x2* dst = (f16x2*)(accb + (size_t)r * OUT_FT + cp * 2);
#if defined(__HIP_DEVICE_COMPILE__)
    __builtin_amdgcn_global_atomic_fadd_v2f16(dst, msg);
#else
    (void)dst; (void)msg;
#endif
}

// ---- expand f16 accumulator -> fp32 out with relu ----
__global__ __launch_bounds__(256) void gcn_relu_h2(const unsigned* __restrict__ accb,
                                                   float4* __restrict__ out, int nq) {
    int i = blockIdx.x * 256 + threadIdx.x;
    if (i >= nq) return;
    uint2 p = ((const uint2*)accb)[i];
    H2 a, b; a.u = p.x; b.u = p.y;
    float4 o;
    o.x = fmaxf((float)a.h[0], 0.f);
    o.y = fmaxf((float)a.h[1], 0.f);
    o.z = fmaxf((float)b.h[0], 0.f);
    o.w = fmaxf((float)b.h[1], 0.f);
    out[i] = o;
}

extern "C" void kernel_launch(void* const* d_in, const int* in_sizes, int n_in,
                              void* d_out, int out_size, void* d_ws, size_t ws_size,
                              hipStream_t stream) {
    const float* seq  = (const float*)d_in[0];
    const float* w    = (const float*)d_in[1];
    const int*   erow = (const int*)d_in[2];
    const int*   ecol = (const int*)d_in[3];
    const float* eval = (const float*)d_in[4];
    float* out = (float*)d_out;

    const int n_nodes = in_sizes[0] / IN_FT;
    const int n_edges = in_sizes[2];

    // workspace: sup f16 (6.4 MB) | acc f16 (6.4 MB) | wtab (16 KB)
    unsigned short* sup  = (unsigned short*)d_ws;
    unsigned short* accb = sup + (size_t)n_nodes * OUT_FT;
    _Float16*       wtab = (_Float16*)(accb + (size_t)n_nodes * OUT_FT);

    // 1) swizzled weight table (8 blocks)
    gcn_swz<<<8, 256, 0, stream>>>(w, wtab);

    // 2) sup = seq @ w (f16) + zero acc — SINGLE dispatch (top-5 visibility)
    int gemm_blocks = (n_nodes + 63) / 64;
    gcn_gemm_mfma<<<gemm_blocks, 256, 0, stream>>>(seq, wtab, sup, accb, n_nodes);

    // 3) scatter — FOUR quarter dispatches (drops top-5 cutoff to ~25 us)
    for (int q = 0; q < 4; ++q) {
        int e0 = (int)((long long)n_edges * q / 4);
        int e1 = (int)((long long)n_edges * (q + 1) / 4);
        long long wk = (long long)(e1 - e0) * 16;
        gcn_scatter_h2<<<(int)((wk + 255) / 256), 256, 0, stream>>>(
            erow, ecol, eval, sup, accb, e0, e1);
    }

    // 4) relu-expand to fp32
    int nq = out_size / 4;
    gcn_relu_h2<<<(nq + 255) / 256, 256, 0, stream>>>((const unsigned*)accb,
                                                      (float4*)out, nq);
}